// Round 4
// baseline (4513.474 us; speedup 1.0000x reference)
//
#include <hip/hip_runtime.h>
#include <cstdint>
#include <cstddef>

#define T_STEPS 1000
#define NS      512
#define HID     128
#define DOUT    20
#define XPAD    129   // x tile row pad (bank-conflict-free lane reads)
#define WPAD    129   // transposed-weight row pad (2 lanes/bank = conflict-free)

// ---------------------------------------------------------------------------
// Pass 0: dense precompute D[row][o] = dot(x_row, Wi1[o][:]) using the exact
// 4-accumulator stride-4 fmaf chain that was verified bit-exact vs numpy in
// round 1 (a_i sums k ≡ i mod 4 ascending; final (a0+a1)+(a2+a3)). DO NOT
// change this order: spike thresholds make the dynamics chaotic to 1-ulp flips.
// ---------------------------------------------------------------------------
extern "C" __global__ void __launch_bounds__(512, 1)
srnn_dense(const float* __restrict__ x, const float* __restrict__ Wi1,
           float* __restrict__ D, int t0, int Tc)
{
    extern __shared__ float sm[];
    float* xs = sm;                    // [128 rows][XPAD]
    float* Wl = sm + 128 * XPAD;       // Wi1 row-major [128][128]
    const int tid = threadIdx.x;
    const int w = tid >> 6, ln = tid & 63;
    const int rb = blockIdx.x * 128;   // chunk-row base

    for (int i = tid; i < HID * HID / 4; i += 512)
        ((float4*)Wl)[i] = ((const float4*)Wi1)[i];
    for (int i = tid; i < 128 * 32; i += 512) {
        int r = i >> 5, kq = i & 31;
        int cr = rb + r;
        int s = cr / Tc, trel = cr - s * Tc;     // chunk row -> (sample, t)
        float4 v = ((const float4*)x)[((size_t)s * T_STEPS + t0 + trel) * 32 + kq];
        float* dst = &xs[r * XPAD + 4 * kq];
        dst[0] = v.x; dst[1] = v.y; dst[2] = v.z; dst[3] = v.w;
    }
    __syncthreads();

    const float* xr0 = xs + ln * XPAD;
    const float* xr1 = xs + (64 + ln) * XPAD;
    for (int og = 0; og < 4; ++og) {
        const int o = 16 * w + 4 * og;
        float a[2][4][4];
        #pragma unroll
        for (int r = 0; r < 2; ++r)
            #pragma unroll
            for (int j = 0; j < 4; ++j)
                #pragma unroll
                for (int i = 0; i < 4; ++i) a[r][j][i] = 0.f;

        #pragma unroll 4
        for (int k = 0; k < HID; k += 4) {
            float4 wv[4];
            #pragma unroll
            for (int j = 0; j < 4; ++j)
                wv[j] = *(const float4*)&Wl[(o + j) * HID + k];   // wave-uniform b128
            float xa0[4], xa1[4];
            #pragma unroll
            for (int i = 0; i < 4; ++i) { xa0[i] = xr0[k + i]; xa1[i] = xr1[k + i]; }
            #pragma unroll
            for (int j = 0; j < 4; ++j) {
                a[0][j][0] = fmaf(xa0[0], wv[j].x, a[0][j][0]);
                a[0][j][1] = fmaf(xa0[1], wv[j].y, a[0][j][1]);
                a[0][j][2] = fmaf(xa0[2], wv[j].z, a[0][j][2]);
                a[0][j][3] = fmaf(xa0[3], wv[j].w, a[0][j][3]);
                a[1][j][0] = fmaf(xa1[0], wv[j].x, a[1][j][0]);
                a[1][j][1] = fmaf(xa1[1], wv[j].y, a[1][j][1]);
                a[1][j][2] = fmaf(xa1[2], wv[j].z, a[1][j][2]);
                a[1][j][3] = fmaf(xa1[3], wv[j].w, a[1][j][3]);
            }
        }
        #pragma unroll
        for (int r = 0; r < 2; ++r) {
            float4 dv;
            dv.x = (a[r][0][0] + a[r][0][1]) + (a[r][0][2] + a[r][0][3]);
            dv.y = (a[r][1][0] + a[r][1][1]) + (a[r][1][2] + a[r][1][3]);
            dv.z = (a[r][2][0] + a[r][2][1]) + (a[r][2][2] + a[r][2][3]);
            dv.w = (a[r][3][0] + a[r][3][1]) + (a[r][3][2] + a[r][3][3]);
            *(float4*)&D[(size_t)(rb + 64 * r + ln) * HID + o] = dv;
        }
    }
}

// ---------------------------------------------------------------------------
// Uniformity helper: force a 64-bit mask into SGPRs so all mask arithmetic
// stays SALU and the per-bit selects compile to scalar ops.
// ---------------------------------------------------------------------------
__device__ __forceinline__ unsigned long long rfl64(unsigned long long v)
{
    unsigned int lo = (unsigned int)__builtin_amdgcn_readfirstlane((int)(v & 0xffffffffULL));
    unsigned int hi = (unsigned int)__builtin_amdgcn_readfirstlane((int)(v >> 32));
    return ((unsigned long long)hi << 32) | (unsigned long long)lo;
}

// Branchless ascending 128-bit bit-walker (dummy index 128 -> zeroed LDS row,
// exact +0.0 at END of ascending chain; harness-validated). Used only in the
// high-occupancy parallel passes.
__device__ __forceinline__ int next128z(unsigned long long& lo, unsigned long long& hi)
{
    unsigned long long l = lo, h = hi;
    int jl = (int)__builtin_ctzll(l | 0x8000000000000000ULL);
    int jh = (int)__builtin_ctzll(h | 0x8000000000000000ULL);
    int j  = l ? jl : (h ? 64 + jh : 128);
    lo = l & (l - 1);
    hi = l ? h : (h & (h - 1));
    return j;
}

// Sparse gather-fold over a [129][WPAD] LDS table. High-occupancy passes only.
__device__ __forceinline__ void walk8(const float* __restrict__ WT, int ln,
                                      unsigned long long m0, unsigned long long m1,
                                      float& rl, float& rh)
{
    unsigned long long lo = m0, hi = m1;
    int n = __popcll(m0) + __popcll(m1);
    while (n > 0) {                           // wave-uniform trip count
        int jj[8];
        #pragma unroll
        for (int u = 0; u < 8; ++u) jj[u] = next128z(lo, hi);
        float va[8], vb[8];
        #pragma unroll
        for (int u = 0; u < 8; ++u) {
            const float* p = WT + jj[u] * WPAD + ln;
            va[u] = p[0];
            vb[u] = p[64];
        }
        #pragma unroll
        for (int u = 0; u < 8; ++u) { rl += va[u]; rh += vb[u]; }
        n -= 8;
    }
}

// Stage [o][j] row-major 128x128 weight matrix into transposed LDS table
// WT[j*WPAD + o] = W[o][j], plus zeroed dummy row j=128.
__device__ __forceinline__ void stage_wt_s(float* WT, const float* __restrict__ W,
                                           int tid, int nthr)
{
    for (int i = tid; i < HID * HID / 4; i += nthr) {
        int o = i >> 5, jq = i & 31;
        float4 v = ((const float4*)W)[i];
        WT[(4 * jq + 0) * WPAD + o] = v.x;
        WT[(4 * jq + 1) * WPAD + o] = v.y;
        WT[(4 * jq + 2) * WPAD + o] = v.z;
        WT[(4 * jq + 3) * WPAD + o] = v.w;
    }
    for (int i = tid; i < WPAD; i += nthr) WT[128 * WPAD + i] = 0.f;
}

// ---------------------------------------------------------------------------
// Shared recurrence kernel (layer 1 AND layer 2 — identical structure):
//   h = ((dense + bi) + r) + bh ; spike = h >= 1 ; mask -> global.
// r = DENSE ascending-j register fold: rl/rh = fmaf(sp_j, w[j], .) for ALL
// j, sp_j in {1.0, 0.0} from the wave-uniform mask (SGPR -> SALU select, one
// v_fmac with SGPR operand per term). Straight-line, branch-free, no memory
// in the chain: the ~128x4cyc dependent-fmaf chain is the deterministic floor.
// Zero terms add +0.0 ascending-interleaved = bit-exact identity (validated
// by round-3 pass which already included zero terms via fmaf(sp,...)).
// One wave per sample; lane ln owns neurons {ln, 64+ln}; weight rows in
// VGPRs (statically indexed, fully unrolled, every element hot every step —
// the allocator-friendly pattern; round-3's branchy fold demoted them).
// ---------------------------------------------------------------------------
extern "C" __global__ void __launch_bounds__(128, 1)
srnn_layer(const float* __restrict__ Din, const float* __restrict__ Wh,
           const float* __restrict__ bi, const float* __restrict__ bh,
           ulonglong2* __restrict__ masks, ulonglong2* __restrict__ state,
           int t0, int Tc, int first)
{
    const int tid = threadIdx.x, w = tid >> 6, ln = tid & 63;
    const int s = 2 * blockIdx.x + w;

    float wl[128], wh[128];                     // Wh rows ln, 64+ln
    const float4* r0 = (const float4*)(Wh + (size_t)ln * HID);
    const float4* r1 = (const float4*)(Wh + (size_t)(64 + ln) * HID);
    #pragma unroll
    for (int q = 0; q < 32; ++q) {
        float4 a = r0[q];
        wl[4 * q + 0] = a.x; wl[4 * q + 1] = a.y;
        wl[4 * q + 2] = a.z; wl[4 * q + 3] = a.w;
        float4 b = r1[q];
        wh[4 * q + 0] = b.x; wh[4 * q + 1] = b.y;
        wh[4 * q + 2] = b.z; wh[4 * q + 3] = b.w;
    }

    const float bil = bi[ln], bih = bi[64 + ln];
    const float bhl = bh[ln], bhh = bh[64 + ln];
    unsigned long long m0 = 0ULL, m1 = 0ULL;
    if (!first) {
        ulonglong2 st = state[s];
        m0 = rfl64(st.x); m1 = rfl64(st.y);     // keep mask phi uniform (SGPR)
    }

    const float* Drow = Din + (size_t)s * Tc * HID;
    float dl[4], dh[4];
    #pragma unroll
    for (int p = 0; p < 4; ++p) {
        int ti = p < Tc ? p : Tc - 1;
        dl[p] = Drow[ti * HID + ln];
        dh[p] = Drow[ti * HID + 64 + ln];
    }

    for (int tt = 0; tt < Tc; tt += 4) {
        #pragma unroll
        for (int u = 0; u < 4; ++u) {
            int t = tt + u;
            if (t >= Tc) break;                       // wave-uniform
            float dense_l = dl[u], dense_h = dh[u];
            int tp = (t + 4 < Tc) ? t + 4 : Tc - 1;   // clamped prefetch
            dl[u] = Drow[tp * HID + ln];
            dh[u] = Drow[tp * HID + 64 + ln];

            float rl = 0.f, rh = 0.f;                 // ascending-j, bit-exact
            #pragma unroll
            for (int j = 0; j < 64; ++j) {
                float sp = ((m0 >> j) & 1ULL) ? 1.0f : 0.0f;
                rl = fmaf(sp, wl[j], rl);
                rh = fmaf(sp, wh[j], rh);
            }
            #pragma unroll
            for (int j = 0; j < 64; ++j) {
                float sp = ((m1 >> j) & 1ULL) ? 1.0f : 0.0f;
                rl = fmaf(sp, wl[64 + j], rl);
                rh = fmaf(sp, wh[64 + j], rh);
            }

            float hl = ((dense_l + bil) + rl) + bhl;  // reference add order
            float hh = ((dense_h + bih) + rh) + bhh;
            m0 = __ballot(hl >= 1.0f);
            m1 = __ballot(hh >= 1.0f);
            if (ln == 0) {
                ulonglong2 mv; mv.x = m0; mv.y = m1;
                masks[(size_t)s * T_STEPS + (t0 + t)] = mv;
            }
        }
    }
    if (ln == 0) { ulonglong2 st; st.x = m0; st.y = m1; state[s] = st; }
}

// ---------------------------------------------------------------------------
// Parallel A-term precompute: D2[row][o] = s1_row @ Wi2^T (ascending sparse
// fold, bit-exact). High occupancy hides the LDS gather latency across waves.
// ---------------------------------------------------------------------------
extern "C" __global__ void __launch_bounds__(512, 1)
srnn_dense2(const ulonglong2* __restrict__ masks, const float* __restrict__ Wi2,
            float* __restrict__ D2, int t0, int Tc)
{
    extern __shared__ float WT[];              // Wi2^T [129][WPAD]
    const int tid = threadIdx.x, w = tid >> 6, ln = tid & 63;

    stage_wt_s(WT, Wi2, tid, 512);
    __syncthreads();

    const int rows = NS * Tc;
    for (int r = blockIdx.x * 8 + w; r < rows; r += gridDim.x * 8) {
        int s = r / Tc, trel = r - s * Tc;
        ulonglong2 mv = masks[(size_t)s * T_STEPS + t0 + trel];
        unsigned long long m0 = rfl64(mv.x), m1 = rfl64(mv.y);
        float rl = 0.f, rh = 0.f;
        walk8(WT, ln, m0, m1, rl, rh);
        D2[(size_t)r * HID + ln]      = rl;
        D2[(size_t)r * HID + 64 + ln] = rh;
    }
}

// ---------------------------------------------------------------------------
// Parallel output-term precompute: d[row][o] = s2_row @ Wo^T for o < 20
// (ascending sparse fold identical to the previously-validated in-chain Wo
// walk). Runs at high occupancy over all (sample,t) rows of the chunk.
// ---------------------------------------------------------------------------
extern "C" __global__ void __launch_bounds__(512, 1)
srnn_dense3(const ulonglong2* __restrict__ masks, const float* __restrict__ Wo,
            float* __restrict__ d, int t0, int Tc)
{
    __shared__ float WOt[129 * DOUT];          // Wo^T [129][20] (row 128 = 0)
    const int tid = threadIdx.x, w = tid >> 6, ln = tid & 63;

    for (int i = tid; i < DOUT * HID / 4; i += 512) {
        int o = i >> 5, jq = i & 31;
        float4 v = ((const float4*)Wo)[i];
        WOt[(4 * jq + 0) * DOUT + o] = v.x; WOt[(4 * jq + 1) * DOUT + o] = v.y;
        WOt[(4 * jq + 2) * DOUT + o] = v.z; WOt[(4 * jq + 3) * DOUT + o] = v.w;
    }
    for (int i = tid; i < DOUT; i += 512) WOt[128 * DOUT + i] = 0.f;
    __syncthreads();

    const int rows = NS * Tc;
    for (int r = blockIdx.x * 8 + w; r < rows; r += gridDim.x * 8) {
        int s = r / Tc, trel = r - s * Tc;
        ulonglong2 mv = masks[(size_t)s * T_STEPS + t0 + trel];
        unsigned long long lo = rfl64(mv.x), hi = rfl64(mv.y);
        if (ln < DOUT) {
            float dd = 0.f;
            int no = __popcll(lo) + __popcll(hi);
            while (no > 0) {
                int jj[8];
                #pragma unroll
                for (int u = 0; u < 8; ++u) jj[u] = next128z(lo, hi);
                float vv[8];
                #pragma unroll
                for (int u = 0; u < 8; ++u) vv[u] = WOt[jj[u] * DOUT + ln];
                #pragma unroll
                for (int u = 0; u < 8; ++u) dd += vv[u];
                no -= 8;
            }
            d[(size_t)r * DOUT + ln] = dd;
        }
    }
}

// ---------------------------------------------------------------------------
// Serial output accumulation, exact reference order per (s,o):
//   acc = (acc + d_t) + bo, t ascending; 8-deep prefetch (proven idiom).
// ---------------------------------------------------------------------------
extern "C" __global__ void __launch_bounds__(128, 1)
srnn_reduce(const float* __restrict__ d, const float* __restrict__ bo,
            float* __restrict__ accbuf, float* __restrict__ out,
            int Tc, int first, int last)
{
    const int tid = threadIdx.x, w = tid >> 6, ln = tid & 63;
    const int s = 2 * blockIdx.x + w;
    if (ln >= DOUT) return;

    const float bol = bo[ln];
    float acc = first ? 0.f : accbuf[s * DOUT + ln];
    const float* drow = d + (size_t)s * Tc * DOUT + ln;

    float pf[8];
    #pragma unroll
    for (int p = 0; p < 8; ++p) { int ti = p < Tc ? p : Tc - 1; pf[p] = drow[ti * DOUT]; }

    for (int tt = 0; tt < Tc; tt += 8) {
        #pragma unroll
        for (int u = 0; u < 8; ++u) {
            int t = tt + u;
            if (t >= Tc) break;                       // uniform among active lanes
            float dv = pf[u];
            int tp = (t + 8 < Tc) ? t + 8 : Tc - 1;
            pf[u] = drow[tp * DOUT];
            acc += dv;                                // (acc + dot) ...
            acc += bol;                               //  ... + bo
        }
    }
    if (last) out[s * DOUT + ln] = acc / (float)T_STEPS;
    else      accbuf[s * DOUT + ln] = acc;
}

// ---------------------------------------------------------------------------
extern "C" void kernel_launch(void* const* d_in, const int* in_sizes, int n_in,
                              void* d_out, int out_size, void* d_ws, size_t ws_size,
                              hipStream_t stream) {
    const float* x   = (const float*)d_in[0];
    const float* Wi1 = (const float*)d_in[1];
    const float* bi1 = (const float*)d_in[2];
    const float* Wh1 = (const float*)d_in[3];
    const float* bh1 = (const float*)d_in[4];
    const float* Wi2 = (const float*)d_in[5];
    const float* bi2 = (const float*)d_in[6];
    const float* Wh2 = (const float*)d_in[7];
    const float* bh2 = (const float*)d_in[8];
    const float* Wo  = (const float*)d_in[9];
    const float* bo  = (const float*)d_in[10];
    float* out = (float*)d_out;

    // ws layout: [masks 8.192MB][st1 8KB][st2 8KB][acc 40KB][D/d chunk buffer]
    const size_t mask_bytes = (size_t)NS * T_STEPS * sizeof(ulonglong2);
    const size_t st_bytes   = (size_t)NS * sizeof(ulonglong2);
    const size_t acc_bytes  = (size_t)NS * DOUT * sizeof(float);
    ulonglong2* masks  = (ulonglong2*)d_ws;
    ulonglong2* state  = (ulonglong2*)((char*)d_ws + mask_bytes);
    ulonglong2* state2 = (ulonglong2*)((char*)d_ws + mask_bytes + st_bytes);
    float* accbuf = (float*)((char*)d_ws + mask_bytes + 2 * st_bytes);
    float* D = (float*)((char*)d_ws + mask_bytes + 2 * st_bytes + acc_bytes);

    const size_t head = mask_bytes + 2 * st_bytes + acc_bytes;
    size_t avail = ws_size > head ? ws_size - head : 0;
    const size_t bytes_per_t = (size_t)NS * HID * sizeof(float);  // 256 KB
    long tcmax = (long)(avail / bytes_per_t);
    static const int divs[] = {1000, 500, 250, 200, 125, 100, 50, 40, 25, 20, 10, 8, 5, 4, 2, 1};
    int Tc = 1;
    for (int i = 0; i < 16; ++i) if (divs[i] <= tcmax) { Tc = divs[i]; break; }

    const int lds0  = (128 * XPAD + HID * HID) * (int)sizeof(float);
    const int ldsd2 = (129 * WPAD) * (int)sizeof(float);
    hipFuncSetAttribute((const void*)srnn_dense,
                        hipFuncAttributeMaxDynamicSharedMemorySize, lds0);
    hipFuncSetAttribute((const void*)srnn_dense2,
                        hipFuncAttributeMaxDynamicSharedMemorySize, ldsd2);

    // Phase 1: dense input-term + layer-1 recurrence (writes s1 masks).
    for (int t0 = 0; t0 < T_STEPS; t0 += Tc) {
        srnn_dense<<<4 * Tc, 512, lds0, stream>>>(x, Wi1, D, t0, Tc);
        srnn_layer<<<NS / 2, 128, 0, stream>>>(D, Wh1, bi1, bh1, masks, state,
                                               t0, Tc, t0 == 0 ? 1 : 0);
    }
    // Phase 2: parallel A-term (s1 @ Wi2^T) + layer-2 recurrence.
    // dense2 consumes the chunk's s1 masks BEFORE srnn_layer overwrites the
    // same slots with s2 masks (stream-ordered, in-place safe).
    for (int t0 = 0; t0 < T_STEPS; t0 += Tc) {
        srnn_dense2<<<512, 512, ldsd2, stream>>>(masks, Wi2, D, t0, Tc);
        srnn_layer<<<NS / 2, 128, 0, stream>>>(D, Wh2, bi2, bh2, masks, state2,
                                               t0, Tc, t0 == 0 ? 1 : 0);
    }
    // Phase 3: parallel output-term (s2 @ Wo^T) + exact serial accumulation.
    for (int t0 = 0; t0 < T_STEPS; t0 += Tc) {
        srnn_dense3<<<512, 512, 0, stream>>>(masks, Wo, D, t0, Tc);
        srnn_reduce<<<NS / 2, 128, 0, stream>>>(D, bo, accbuf, out, Tc,
                                                t0 == 0 ? 1 : 0,
                                                t0 + Tc >= T_STEPS ? 1 : 0);
    }
}

// Round 6
// 2844.168 us; speedup vs baseline: 1.5869x; 1.5869x over previous
//
#include <hip/hip_runtime.h>
#include <cstdint>
#include <cstddef>

#define T_STEPS 1000
#define NS      512
#define HID     128
#define DOUT    20
#define XPAD    129   // x tile row pad (bank-conflict-free lane reads)
#define WPAD    129   // transposed-weight row pad (2 lanes/bank = conflict-free)

// ---------------------------------------------------------------------------
// Pass 0: dense precompute D[row][o] = dot(x_row, Wi1[o][:]) using the exact
// 4-accumulator stride-4 fmaf chain that was verified bit-exact vs numpy in
// round 1 (a_i sums k ≡ i mod 4 ascending; final (a0+a1)+(a2+a3)). DO NOT
// change this order: spike thresholds make the dynamics chaotic to 1-ulp flips.
// ---------------------------------------------------------------------------
extern "C" __global__ void __launch_bounds__(512, 1)
srnn_dense(const float* __restrict__ x, const float* __restrict__ Wi1,
           float* __restrict__ D, int t0, int Tc)
{
    extern __shared__ float sm[];
    float* xs = sm;                    // [128 rows][XPAD]
    float* Wl = sm + 128 * XPAD;       // Wi1 row-major [128][128]
    const int tid = threadIdx.x;
    const int w = tid >> 6, ln = tid & 63;
    const int rb = blockIdx.x * 128;   // chunk-row base

    for (int i = tid; i < HID * HID / 4; i += 512)
        ((float4*)Wl)[i] = ((const float4*)Wi1)[i];
    for (int i = tid; i < 128 * 32; i += 512) {
        int r = i >> 5, kq = i & 31;
        int cr = rb + r;
        int s = cr / Tc, trel = cr - s * Tc;     // chunk row -> (sample, t)
        float4 v = ((const float4*)x)[((size_t)s * T_STEPS + t0 + trel) * 32 + kq];
        float* dst = &xs[r * XPAD + 4 * kq];
        dst[0] = v.x; dst[1] = v.y; dst[2] = v.z; dst[3] = v.w;
    }
    __syncthreads();

    const float* xr0 = xs + ln * XPAD;
    const float* xr1 = xs + (64 + ln) * XPAD;
    for (int og = 0; og < 4; ++og) {
        const int o = 16 * w + 4 * og;
        float a[2][4][4];
        #pragma unroll
        for (int r = 0; r < 2; ++r)
            #pragma unroll
            for (int j = 0; j < 4; ++j)
                #pragma unroll
                for (int i = 0; i < 4; ++i) a[r][j][i] = 0.f;

        #pragma unroll 4
        for (int k = 0; k < HID; k += 4) {
            float4 wv[4];
            #pragma unroll
            for (int j = 0; j < 4; ++j)
                wv[j] = *(const float4*)&Wl[(o + j) * HID + k];   // wave-uniform b128
            float xa0[4], xa1[4];
            #pragma unroll
            for (int i = 0; i < 4; ++i) { xa0[i] = xr0[k + i]; xa1[i] = xr1[k + i]; }
            #pragma unroll
            for (int j = 0; j < 4; ++j) {
                a[0][j][0] = fmaf(xa0[0], wv[j].x, a[0][j][0]);
                a[0][j][1] = fmaf(xa0[1], wv[j].y, a[0][j][1]);
                a[0][j][2] = fmaf(xa0[2], wv[j].z, a[0][j][2]);
                a[0][j][3] = fmaf(xa0[3], wv[j].w, a[0][j][3]);
                a[1][j][0] = fmaf(xa1[0], wv[j].x, a[1][j][0]);
                a[1][j][1] = fmaf(xa1[1], wv[j].y, a[1][j][1]);
                a[1][j][2] = fmaf(xa1[2], wv[j].z, a[1][j][2]);
                a[1][j][3] = fmaf(xa1[3], wv[j].w, a[1][j][3]);
            }
        }
        #pragma unroll
        for (int r = 0; r < 2; ++r) {
            float4 dv;
            dv.x = (a[r][0][0] + a[r][0][1]) + (a[r][0][2] + a[r][0][3]);
            dv.y = (a[r][1][0] + a[r][1][1]) + (a[r][1][2] + a[r][1][3]);
            dv.z = (a[r][2][0] + a[r][2][1]) + (a[r][2][2] + a[r][2][3]);
            dv.w = (a[r][3][0] + a[r][3][1]) + (a[r][3][2] + a[r][3][3]);
            *(float4*)&D[(size_t)(rb + 64 * r + ln) * HID + o] = dv;
        }
    }
}

// ---------------------------------------------------------------------------
// Uniformity helper: force a 64-bit mask into SGPRs so all mask arithmetic
// (ctz / clear-lowest / popcnt / selects) stays SALU.
// ---------------------------------------------------------------------------
__device__ __forceinline__ unsigned long long rfl64(unsigned long long v)
{
    unsigned int lo = (unsigned int)__builtin_amdgcn_readfirstlane((int)(v & 0xffffffffULL));
    unsigned int hi = (unsigned int)__builtin_amdgcn_readfirstlane((int)(v >> 32));
    return ((unsigned long long)hi << 32) | (unsigned long long)lo;
}

// Branchless ascending 128-bit bit-walker (dummy index 128 -> zeroed LDS row,
// exact +0.0 at END of ascending chain; harness-validated r1/r2/r4).
__device__ __forceinline__ int next128z(unsigned long long& lo, unsigned long long& hi)
{
    unsigned long long l = lo, h = hi;
    int jl = (int)__builtin_ctzll(l | 0x8000000000000000ULL);
    int jh = (int)__builtin_ctzll(h | 0x8000000000000000ULL);
    int j  = l ? jl : (h ? 64 + jh : 128);
    lo = l & (l - 1);
    hi = l ? h : (h & (h - 1));
    return j;
}

// ---------------------------------------------------------------------------
// Raw LDS loads via inline asm. asm volatile blocks keep PROGRAM ORDER among
// themselves -> all batch loads issue back-to-back BEFORE the single waitcnt;
// the compiler cannot sink them next to their uses (which it provably does to
// plain-C LDS gathers at 1-wave occupancy: rounds 0-2). Address = low 32 bits
// of the generic pointer (LDS aperture is 4GiB-aligned on gfx9+ -> truncation
// yields the LDS byte offset; same idiom as the m214 attn ladder).
// "=&v" early-clobber: batch outputs can never alias later batch addresses.
// ---------------------------------------------------------------------------
__device__ __forceinline__ float ds_ld(unsigned int a)
{
    float r;
    asm volatile("ds_read_b32 %0, %1" : "=&v"(r) : "v"(a));
    return r;
}
__device__ __forceinline__ float ds_ld_off256(unsigned int a)
{
    float r;
    asm volatile("ds_read_b32 %0, %1 offset:256" : "=&v"(r) : "v"(a));
    return r;
}

// Stage [o][j] row-major 128x128 weight matrix into transposed LDS table
// WT[j*WPAD + o] = W[o][j], plus zeroed dummy row j=128.
__device__ __forceinline__ void stage_wt_s(float* WT, const float* __restrict__ W,
                                           int tid, int nthr)
{
    for (int i = tid; i < HID * HID / 4; i += nthr) {
        int o = i >> 5, jq = i & 31;
        float4 v = ((const float4*)W)[i];
        WT[(4 * jq + 0) * WPAD + o] = v.x;
        WT[(4 * jq + 1) * WPAD + o] = v.y;
        WT[(4 * jq + 2) * WPAD + o] = v.z;
        WT[(4 * jq + 3) * WPAD + o] = v.w;
    }
    for (int i = tid; i < WPAD; i += nthr) WT[128 * WPAD + i] = 0.f;
}

// Sparse gather-fold (plain C) for HIGH-OCCUPANCY passes only, where TLP
// hides the per-wave serialization (dense2/dense3).
__device__ __forceinline__ void walk8(const float* __restrict__ WT, int ln,
                                      unsigned long long m0, unsigned long long m1,
                                      float& rl, float& rh)
{
    unsigned long long lo = m0, hi = m1;
    int n = __popcll(m0) + __popcll(m1);
    while (n > 0) {                           // wave-uniform trip count
        int jj[8];
        #pragma unroll
        for (int u = 0; u < 8; ++u) jj[u] = next128z(lo, hi);
        float va[8], vb[8];
        #pragma unroll
        for (int u = 0; u < 8; ++u) {
            const float* p = WT + jj[u] * WPAD + ln;
            va[u] = p[0];
            vb[u] = p[64];
        }
        #pragma unroll
        for (int u = 0; u < 8; ++u) { rl += va[u]; rh += vb[u]; }
        n -= 8;
    }
}

// ---------------------------------------------------------------------------
// Shared recurrence kernel (layer 1 AND layer 2):
//   h = ((dense + bi) + r) + bh ; spike = h >= 1 ; mask -> global.
// r = sparse ascending fold over the LDS weight table, batched 16 indices at
// a time through inline-asm ds_read_b32 (32 loads in flight -> ONE LDS
// latency per batch instead of one per spike). Extraction is SALU (masks are
// SGPR-uniform). Fold order identical to all passing rounds: ascending j,
// trailing +0.0 dummy terms.
// ---------------------------------------------------------------------------
extern "C" __global__ void __launch_bounds__(128, 1)
srnn_layer(const float* __restrict__ Din, const float* __restrict__ Wh,
           const float* __restrict__ bi, const float* __restrict__ bh,
           ulonglong2* __restrict__ masks, ulonglong2* __restrict__ state,
           int t0, int Tc, int first)
{
    extern __shared__ float WT[];      // [129][WPAD]
    const int tid = threadIdx.x, w = tid >> 6, ln = tid & 63;
    const int s = 2 * blockIdx.x + w;

    stage_wt_s(WT, Wh, tid, 128);

    const float bil = bi[ln], bih = bi[64 + ln];
    const float bhl = bh[ln], bhh = bh[64 + ln];
    unsigned long long m0 = 0ULL, m1 = 0ULL;
    if (!first) {
        ulonglong2 st = state[s];
        m0 = rfl64(st.x); m1 = rfl64(st.y);     // keep mask phi uniform (SGPR)
    }

    // per-lane LDS byte base: &WT[ln] (low 32 bits of generic addr = LDS offset)
    const unsigned int lbase = (unsigned int)(size_t)(WT + ln);

    const float* Drow = Din + (size_t)s * Tc * HID;
    float dl[4], dh[4];
    #pragma unroll
    for (int p = 0; p < 4; ++p) {
        int ti = p < Tc ? p : Tc - 1;
        dl[p] = Drow[ti * HID + ln];
        dh[p] = Drow[ti * HID + 64 + ln];
    }
    __syncthreads();

    for (int tt = 0; tt < Tc; tt += 4) {
        #pragma unroll
        for (int u = 0; u < 4; ++u) {
            int t = tt + u;
            if (t >= Tc) break;                       // wave-uniform
            float dense_l = dl[u], dense_h = dh[u];
            int tp = (t + 4 < Tc) ? t + 4 : Tc - 1;   // clamped prefetch
            dl[u] = Drow[tp * HID + ln];
            dh[u] = Drow[tp * HID + 64 + ln];

            float rl = 0.f, rh = 0.f;                 // ascending-j, bit-exact
            {
                unsigned long long lo = m0, hi = m1;
                int n = __popcll(m0) + __popcll(m1);
                while (n > 0) {                       // wave-uniform trip count
                    float va[16], vb[16];
                    #pragma unroll
                    for (int q = 0; q < 16; ++q) {
                        int j = next128z(lo, hi);     // SALU, ascending
                        unsigned int a = lbase + (unsigned int)(j * (WPAD * 4));
                        va[q] = ds_ld(a);             // in-order issue
                        vb[q] = ds_ld_off256(a);      // +64 floats = +256 B
                    }
                    asm volatile("s_waitcnt lgkmcnt(0)" ::: "memory");
                    __builtin_amdgcn_sched_barrier(0);  // rule #18: pin fold after wait
                    #pragma unroll
                    for (int q = 0; q < 16; ++q) { rl += va[q]; rh += vb[q]; }
                    n -= 16;
                }
            }

            float hl = ((dense_l + bil) + rl) + bhl;  // reference add order
            float hh = ((dense_h + bih) + rh) + bhh;
            m0 = __ballot(hl >= 1.0f);
            m1 = __ballot(hh >= 1.0f);
            if (ln == 0) {
                ulonglong2 mv; mv.x = m0; mv.y = m1;
                masks[(size_t)s * T_STEPS + (t0 + t)] = mv;
            }
        }
    }
    if (ln == 0) { ulonglong2 st; st.x = m0; st.y = m1; state[s] = st; }
}

// ---------------------------------------------------------------------------
// Parallel A-term precompute: D2[row][o] = s1_row @ Wi2^T (ascending sparse
// fold, bit-exact). High occupancy hides the LDS gather latency across waves.
// ---------------------------------------------------------------------------
extern "C" __global__ void __launch_bounds__(512, 1)
srnn_dense2(const ulonglong2* __restrict__ masks, const float* __restrict__ Wi2,
            float* __restrict__ D2, int t0, int Tc)
{
    extern __shared__ float WT[];              // Wi2^T [129][WPAD]
    const int tid = threadIdx.x, w = tid >> 6, ln = tid & 63;

    stage_wt_s(WT, Wi2, tid, 512);
    __syncthreads();

    const int rows = NS * Tc;
    for (int r = blockIdx.x * 8 + w; r < rows; r += gridDim.x * 8) {
        int s = r / Tc, trel = r - s * Tc;
        ulonglong2 mv = masks[(size_t)s * T_STEPS + t0 + trel];
        unsigned long long m0 = rfl64(mv.x), m1 = rfl64(mv.y);
        float rl = 0.f, rh = 0.f;
        walk8(WT, ln, m0, m1, rl, rh);
        D2[(size_t)r * HID + ln]      = rl;
        D2[(size_t)r * HID + 64 + ln] = rh;
    }
}

// ---------------------------------------------------------------------------
// Parallel output-term precompute: d[row][o] = s2_row @ Wo^T for o < 20
// (ascending sparse fold; trailing zeros bit-exact). High occupancy.
// ---------------------------------------------------------------------------
extern "C" __global__ void __launch_bounds__(512, 1)
srnn_dense3(const ulonglong2* __restrict__ masks, const float* __restrict__ Wo,
            float* __restrict__ d, int t0, int Tc)
{
    __shared__ float WOt[129 * DOUT];          // Wo^T [129][20] (row 128 = 0)
    const int tid = threadIdx.x, w = tid >> 6, ln = tid & 63;

    for (int i = tid; i < DOUT * HID / 4; i += 512) {
        int o = i >> 5, jq = i & 31;
        float4 v = ((const float4*)Wo)[i];
        WOt[(4 * jq + 0) * DOUT + o] = v.x; WOt[(4 * jq + 1) * DOUT + o] = v.y;
        WOt[(4 * jq + 2) * DOUT + o] = v.z; WOt[(4 * jq + 3) * DOUT + o] = v.w;
    }
    for (int i = tid; i < DOUT; i += 512) WOt[128 * DOUT + i] = 0.f;
    __syncthreads();

    const int rows = NS * Tc;
    for (int r = blockIdx.x * 8 + w; r < rows; r += gridDim.x * 8) {
        int s = r / Tc, trel = r - s * Tc;
        ulonglong2 mv = masks[(size_t)s * T_STEPS + t0 + trel];
        unsigned long long lo = rfl64(mv.x), hi = rfl64(mv.y);
        if (ln < DOUT) {
            float dd = 0.f;
            int no = __popcll(lo) + __popcll(hi);
            while (no > 0) {
                int jj[8];
                #pragma unroll
                for (int u = 0; u < 8; ++u) jj[u] = next128z(lo, hi);
                float vv[8];
                #pragma unroll
                for (int u = 0; u < 8; ++u) vv[u] = WOt[jj[u] * DOUT + ln];
                #pragma unroll
                for (int u = 0; u < 8; ++u) dd += vv[u];
                no -= 8;
            }
            d[(size_t)r * DOUT + ln] = dd;
        }
    }
}

// ---------------------------------------------------------------------------
// Serial output accumulation, exact reference order per (s,o):
//   acc = (acc + d_t) + bo, t ascending; 8-deep prefetch (proven idiom).
// ---------------------------------------------------------------------------
extern "C" __global__ void __launch_bounds__(128, 1)
srnn_reduce(const float* __restrict__ d, const float* __restrict__ bo,
            float* __restrict__ accbuf, float* __restrict__ out,
            int Tc, int first, int last)
{
    const int tid = threadIdx.x, w = tid >> 6, ln = tid & 63;
    const int s = 2 * blockIdx.x + w;
    if (ln >= DOUT) return;

    const float bol = bo[ln];
    float acc = first ? 0.f : accbuf[s * DOUT + ln];
    const float* drow = d + (size_t)s * Tc * DOUT + ln;

    float pf[8];
    #pragma unroll
    for (int p = 0; p < 8; ++p) { int ti = p < Tc ? p : Tc - 1; pf[p] = drow[ti * DOUT]; }

    for (int tt = 0; tt < Tc; tt += 8) {
        #pragma unroll
        for (int u = 0; u < 8; ++u) {
            int t = tt + u;
            if (t >= Tc) break;                       // uniform among active lanes
            float dv = pf[u];
            int tp = (t + 8 < Tc) ? t + 8 : Tc - 1;
            pf[u] = drow[tp * DOUT];
            acc += dv;                                // (acc + dot) ...
            acc += bol;                               //  ... + bo
        }
    }
    if (last) out[s * DOUT + ln] = acc / (float)T_STEPS;
    else      accbuf[s * DOUT + ln] = acc;
}

// ---------------------------------------------------------------------------
extern "C" void kernel_launch(void* const* d_in, const int* in_sizes, int n_in,
                              void* d_out, int out_size, void* d_ws, size_t ws_size,
                              hipStream_t stream) {
    const float* x   = (const float*)d_in[0];
    const float* Wi1 = (const float*)d_in[1];
    const float* bi1 = (const float*)d_in[2];
    const float* Wh1 = (const float*)d_in[3];
    const float* bh1 = (const float*)d_in[4];
    const float* Wi2 = (const float*)d_in[5];
    const float* bi2 = (const float*)d_in[6];
    const float* Wh2 = (const float*)d_in[7];
    const float* bh2 = (const float*)d_in[8];
    const float* Wo  = (const float*)d_in[9];
    const float* bo  = (const float*)d_in[10];
    float* out = (float*)d_out;

    // ws layout: [masks 8.192MB][st1 8KB][st2 8KB][acc 40KB][D/d chunk buffer]
    const size_t mask_bytes = (size_t)NS * T_STEPS * sizeof(ulonglong2);
    const size_t st_bytes   = (size_t)NS * sizeof(ulonglong2);
    const size_t acc_bytes  = (size_t)NS * DOUT * sizeof(float);
    ulonglong2* masks  = (ulonglong2*)d_ws;
    ulonglong2* state  = (ulonglong2*)((char*)d_ws + mask_bytes);
    ulonglong2* state2 = (ulonglong2*)((char*)d_ws + mask_bytes + st_bytes);
    float* accbuf = (float*)((char*)d_ws + mask_bytes + 2 * st_bytes);
    float* D = (float*)((char*)d_ws + mask_bytes + 2 * st_bytes + acc_bytes);

    const size_t head = mask_bytes + 2 * st_bytes + acc_bytes;
    size_t avail = ws_size > head ? ws_size - head : 0;
    const size_t bytes_per_t = (size_t)NS * HID * sizeof(float);  // 256 KB
    long tcmax = (long)(avail / bytes_per_t);
    static const int divs[] = {1000, 500, 250, 200, 125, 100, 50, 40, 25, 20, 10, 8, 5, 4, 2, 1};
    int Tc = 1;
    for (int i = 0; i < 16; ++i) if (divs[i] <= tcmax) { Tc = divs[i]; break; }

    const int lds0  = (128 * XPAD + HID * HID) * (int)sizeof(float);
    const int lds1  = (129 * WPAD) * (int)sizeof(float);
    hipFuncSetAttribute((const void*)srnn_dense,
                        hipFuncAttributeMaxDynamicSharedMemorySize, lds0);
    hipFuncSetAttribute((const void*)srnn_layer,
                        hipFuncAttributeMaxDynamicSharedMemorySize, lds1);
    hipFuncSetAttribute((const void*)srnn_dense2,
                        hipFuncAttributeMaxDynamicSharedMemorySize, lds1);

    // Phase 1: dense input-term + layer-1 recurrence (writes s1 masks).
    for (int t0 = 0; t0 < T_STEPS; t0 += Tc) {
        srnn_dense<<<4 * Tc, 512, lds0, stream>>>(x, Wi1, D, t0, Tc);
        srnn_layer<<<NS / 2, 128, lds1, stream>>>(D, Wh1, bi1, bh1, masks, state,
                                                  t0, Tc, t0 == 0 ? 1 : 0);
    }
    // Phase 2: parallel A-term (s1 @ Wi2^T) + layer-2 recurrence.
    // dense2 consumes the chunk's s1 masks BEFORE srnn_layer overwrites the
    // same slots with s2 masks (stream-ordered, in-place safe).
    for (int t0 = 0; t0 < T_STEPS; t0 += Tc) {
        srnn_dense2<<<512, 512, lds1, stream>>>(masks, Wi2, D, t0, Tc);
        srnn_layer<<<NS / 2, 128, lds1, stream>>>(D, Wh2, bi2, bh2, masks, state2,
                                                  t0, Tc, t0 == 0 ? 1 : 0);
    }
    // Phase 3: parallel output-term (s2 @ Wo^T) + exact serial accumulation.
    for (int t0 = 0; t0 < T_STEPS; t0 += Tc) {
        srnn_dense3<<<512, 512, 0, stream>>>(masks, Wo, D, t0, Tc);
        srnn_reduce<<<NS / 2, 128, 0, stream>>>(D, bo, accbuf, out, Tc,
                                                t0 == 0 ? 1 : 0,
                                                t0 + Tc >= T_STEPS ? 1 : 0);
    }
}

// Round 7
// 2828.178 us; speedup vs baseline: 1.5959x; 1.0057x over previous
//
#include <hip/hip_runtime.h>
#include <cstdint>
#include <cstddef>

#define T_STEPS 1000
#define NS      512
#define HID     128
#define DOUT    20
#define XPAD    129   // x tile row pad (bank-conflict-free lane reads)
#define WPAD    129   // transposed-weight row pad (2 lanes/bank = conflict-free)

// ---------------------------------------------------------------------------
// Pass 0: dense precompute D[row][o] = dot(x_row, Wi1[o][:]) using the exact
// 4-accumulator stride-4 fmaf chain that was verified bit-exact vs numpy in
// round 1 (a_i sums k ≡ i mod 4 ascending; final (a0+a1)+(a2+a3)). DO NOT
// change this order: spike thresholds make the dynamics chaotic to 1-ulp flips.
// ---------------------------------------------------------------------------
extern "C" __global__ void __launch_bounds__(512, 1)
srnn_dense(const float* __restrict__ x, const float* __restrict__ Wi1,
           float* __restrict__ D, int t0, int Tc)
{
    extern __shared__ float sm[];
    float* xs = sm;                    // [128 rows][XPAD]
    float* Wl = sm + 128 * XPAD;       // Wi1 row-major [128][128]
    const int tid = threadIdx.x;
    const int w = tid >> 6, ln = tid & 63;
    const int rb = blockIdx.x * 128;   // chunk-row base

    for (int i = tid; i < HID * HID / 4; i += 512)
        ((float4*)Wl)[i] = ((const float4*)Wi1)[i];
    for (int i = tid; i < 128 * 32; i += 512) {
        int r = i >> 5, kq = i & 31;
        int cr = rb + r;
        int s = cr / Tc, trel = cr - s * Tc;     // chunk row -> (sample, t)
        float4 v = ((const float4*)x)[((size_t)s * T_STEPS + t0 + trel) * 32 + kq];
        float* dst = &xs[r * XPAD + 4 * kq];
        dst[0] = v.x; dst[1] = v.y; dst[2] = v.z; dst[3] = v.w;
    }
    __syncthreads();

    const float* xr0 = xs + ln * XPAD;
    const float* xr1 = xs + (64 + ln) * XPAD;
    for (int og = 0; og < 4; ++og) {
        const int o = 16 * w + 4 * og;
        float a[2][4][4];
        #pragma unroll
        for (int r = 0; r < 2; ++r)
            #pragma unroll
            for (int j = 0; j < 4; ++j)
                #pragma unroll
                for (int i = 0; i < 4; ++i) a[r][j][i] = 0.f;

        #pragma unroll 4
        for (int k = 0; k < HID; k += 4) {
            float4 wv[4];
            #pragma unroll
            for (int j = 0; j < 4; ++j)
                wv[j] = *(const float4*)&Wl[(o + j) * HID + k];   // wave-uniform b128
            float xa0[4], xa1[4];
            #pragma unroll
            for (int i = 0; i < 4; ++i) { xa0[i] = xr0[k + i]; xa1[i] = xr1[k + i]; }
            #pragma unroll
            for (int j = 0; j < 4; ++j) {
                a[0][j][0] = fmaf(xa0[0], wv[j].x, a[0][j][0]);
                a[0][j][1] = fmaf(xa0[1], wv[j].y, a[0][j][1]);
                a[0][j][2] = fmaf(xa0[2], wv[j].z, a[0][j][2]);
                a[0][j][3] = fmaf(xa0[3], wv[j].w, a[0][j][3]);
                a[1][j][0] = fmaf(xa1[0], wv[j].x, a[1][j][0]);
                a[1][j][1] = fmaf(xa1[1], wv[j].y, a[1][j][1]);
                a[1][j][2] = fmaf(xa1[2], wv[j].z, a[1][j][2]);
                a[1][j][3] = fmaf(xa1[3], wv[j].w, a[1][j][3]);
            }
        }
        #pragma unroll
        for (int r = 0; r < 2; ++r) {
            float4 dv;
            dv.x = (a[r][0][0] + a[r][0][1]) + (a[r][0][2] + a[r][0][3]);
            dv.y = (a[r][1][0] + a[r][1][1]) + (a[r][1][2] + a[r][1][3]);
            dv.z = (a[r][2][0] + a[r][2][1]) + (a[r][2][2] + a[r][2][3]);
            dv.w = (a[r][3][0] + a[r][3][1]) + (a[r][3][2] + a[r][3][3]);
            *(float4*)&D[(size_t)(rb + 64 * r + ln) * HID + o] = dv;
        }
    }
}

// ---------------------------------------------------------------------------
// Uniformity helper: force a 64-bit mask into SGPRs so all mask arithmetic
// (ctz / clear-lowest / popcnt / selects) stays SALU.
// ---------------------------------------------------------------------------
__device__ __forceinline__ unsigned long long rfl64(unsigned long long v)
{
    unsigned int lo = (unsigned int)__builtin_amdgcn_readfirstlane((int)(v & 0xffffffffULL));
    unsigned int hi = (unsigned int)__builtin_amdgcn_readfirstlane((int)(v >> 32));
    return ((unsigned long long)hi << 32) | (unsigned long long)lo;
}

// Branchless ascending 128-bit bit-walker (dummy index 128 -> zeroed LDS row,
// exact +0.0 at END of ascending chain; harness-validated r1/r2/r4/r6).
__device__ __forceinline__ int next128z(unsigned long long& lo, unsigned long long& hi)
{
    unsigned long long l = lo, h = hi;
    int jl = (int)__builtin_ctzll(l | 0x8000000000000000ULL);
    int jh = (int)__builtin_ctzll(h | 0x8000000000000000ULL);
    int j  = l ? jl : (h ? 64 + jh : 128);
    lo = l & (l - 1);
    hi = l ? h : (h & (h - 1));
    return j;
}

// Stage [o][j] row-major 128x128 weight matrix into transposed LDS table
// WT[j*WPAD + o] = W[o][j], plus zeroed dummy row j=128.
__device__ __forceinline__ void stage_wt_s(float* WT, const float* __restrict__ W,
                                           int tid, int nthr)
{
    for (int i = tid; i < HID * HID / 4; i += nthr) {
        int o = i >> 5, jq = i & 31;
        float4 v = ((const float4*)W)[i];
        WT[(4 * jq + 0) * WPAD + o] = v.x;
        WT[(4 * jq + 1) * WPAD + o] = v.y;
        WT[(4 * jq + 2) * WPAD + o] = v.z;
        WT[(4 * jq + 3) * WPAD + o] = v.w;
    }
    for (int i = tid; i < WPAD; i += nthr) WT[128 * WPAD + i] = 0.f;
}

// Sparse gather-fold (plain C) for HIGH-OCCUPANCY passes only, where TLP
// hides the per-wave serialization (dense2/dense3).
__device__ __forceinline__ void walk8(const float* __restrict__ WT, int ln,
                                      unsigned long long m0, unsigned long long m1,
                                      float& rl, float& rh)
{
    unsigned long long lo = m0, hi = m1;
    int n = __popcll(m0) + __popcll(m1);
    while (n > 0) {                           // wave-uniform trip count
        int jj[8];
        #pragma unroll
        for (int u = 0; u < 8; ++u) jj[u] = next128z(lo, hi);
        float va[8], vb[8];
        #pragma unroll
        for (int u = 0; u < 8; ++u) {
            const float* p = WT + jj[u] * WPAD + ln;
            va[u] = p[0];
            vb[u] = p[64];
        }
        #pragma unroll
        for (int u = 0; u < 8; ++u) { rl += va[u]; rh += vb[u]; }
        n -= 8;
    }
}

// 8 ds_read_b32 issued in ONE asm block (outputs are NAMED scalars at the
// call site -> cannot be demoted to scratch, the r6 failure). Program order
// of asm volatile blocks guarantees all reads issue before the waitcnt.
#define DS_GATHER8(o0,o1,o2,o3,o4,o5,o6,o7, a0,a1,a2,a3,a4,a5,a6,a7)          \
    asm volatile(                                                             \
        "ds_read_b32 %0, %8\n\t"                                              \
        "ds_read_b32 %1, %9\n\t"                                              \
        "ds_read_b32 %2, %10\n\t"                                             \
        "ds_read_b32 %3, %11\n\t"                                             \
        "ds_read_b32 %4, %12\n\t"                                             \
        "ds_read_b32 %5, %13\n\t"                                             \
        "ds_read_b32 %6, %14\n\t"                                             \
        "ds_read_b32 %7, %15\n\t"                                             \
        : "=&v"(o0), "=&v"(o1), "=&v"(o2), "=&v"(o3),                         \
          "=&v"(o4), "=&v"(o5), "=&v"(o6), "=&v"(o7)                          \
        : "v"(a0), "v"(a1), "v"(a2), "v"(a3),                                 \
          "v"(a4), "v"(a5), "v"(a6), "v"(a7))

#define DS_GATHER8_OFF256(o0,o1,o2,o3,o4,o5,o6,o7, a0,a1,a2,a3,a4,a5,a6,a7)   \
    asm volatile(                                                             \
        "ds_read_b32 %0, %8 offset:256\n\t"                                   \
        "ds_read_b32 %1, %9 offset:256\n\t"                                   \
        "ds_read_b32 %2, %10 offset:256\n\t"                                  \
        "ds_read_b32 %3, %11 offset:256\n\t"                                  \
        "ds_read_b32 %4, %12 offset:256\n\t"                                  \
        "ds_read_b32 %5, %13 offset:256\n\t"                                  \
        "ds_read_b32 %6, %14 offset:256\n\t"                                  \
        "ds_read_b32 %7, %15 offset:256\n\t"                                  \
        : "=&v"(o0), "=&v"(o1), "=&v"(o2), "=&v"(o3),                         \
          "=&v"(o4), "=&v"(o5), "=&v"(o6), "=&v"(o7)                          \
        : "v"(a0), "v"(a1), "v"(a2), "v"(a3),                                 \
          "v"(a4), "v"(a5), "v"(a6), "v"(a7))

// ---------------------------------------------------------------------------
// Shared recurrence kernel (layer 1 AND layer 2):
//   h = ((dense + bi) + r) + bh ; spike = h >= 1 ; mask -> global.
// r = sparse ascending fold; up to 16 indices extracted on SALU, 32
// ds_read_b32 issued back-to-back (4 asm blocks of 8, named-scalar outputs),
// ONE lgkmcnt(0) + sched_barrier(0), then the ascending fold. One LDS
// round-trip per batch instead of one per spike. Fold order identical to all
// passing rounds: ascending j, trailing +0.0 dummy terms.
// ---------------------------------------------------------------------------
extern "C" __global__ void __launch_bounds__(128, 1)
srnn_layer(const float* __restrict__ Din, const float* __restrict__ Wh,
           const float* __restrict__ bi, const float* __restrict__ bh,
           ulonglong2* __restrict__ masks, ulonglong2* __restrict__ state,
           int t0, int Tc, int first)
{
    extern __shared__ float WT[];      // [129][WPAD]
    const int tid = threadIdx.x, w = tid >> 6, ln = tid & 63;
    const int s = 2 * blockIdx.x + w;

    stage_wt_s(WT, Wh, tid, 128);

    const float bil = bi[ln], bih = bi[64 + ln];
    const float bhl = bh[ln], bhh = bh[64 + ln];
    unsigned long long m0 = 0ULL, m1 = 0ULL;
    if (!first) {
        ulonglong2 st = state[s];
        m0 = rfl64(st.x); m1 = rfl64(st.y);     // keep mask phi uniform (SGPR)
    }

    // per-lane LDS byte base: &WT[ln] (low 32 bits of generic addr = LDS offset;
    // idiom numerically validated in r6)
    const unsigned int lbase = (unsigned int)(size_t)(WT + ln);

    const float* Drow = Din + (size_t)s * Tc * HID;
    float dl[4], dh[4];
    #pragma unroll
    for (int p = 0; p < 4; ++p) {
        int ti = p < Tc ? p : Tc - 1;
        dl[p] = Drow[ti * HID + ln];
        dh[p] = Drow[ti * HID + 64 + ln];
    }
    __syncthreads();

    for (int tt = 0; tt < Tc; tt += 4) {
        #pragma unroll
        for (int u = 0; u < 4; ++u) {
            int t = tt + u;
            if (t >= Tc) break;                       // wave-uniform
            float dense_l = dl[u], dense_h = dh[u];
            int tp = (t + 4 < Tc) ? t + 4 : Tc - 1;   // clamped prefetch
            dl[u] = Drow[tp * HID + ln];
            dh[u] = Drow[tp * HID + 64 + ln];

            float rl = 0.f, rh = 0.f;                 // ascending-j, bit-exact
            {
                unsigned long long lo = m0, hi = m1;
                int n = __popcll(m0) + __popcll(m1);
                while (n > 0) {                       // wave-uniform trip count
                    // extract 16 ascending indices (SALU; dummy=128 -> zero row)
                    int j0  = next128z(lo, hi), j1  = next128z(lo, hi);
                    int j2  = next128z(lo, hi), j3  = next128z(lo, hi);
                    int j4  = next128z(lo, hi), j5  = next128z(lo, hi);
                    int j6  = next128z(lo, hi), j7  = next128z(lo, hi);
                    int j8  = next128z(lo, hi), j9  = next128z(lo, hi);
                    int j10 = next128z(lo, hi), j11 = next128z(lo, hi);
                    int j12 = next128z(lo, hi), j13 = next128z(lo, hi);
                    int j14 = next128z(lo, hi), j15 = next128z(lo, hi);
                    unsigned int a0  = lbase + (unsigned)(j0  * (WPAD * 4));
                    unsigned int a1  = lbase + (unsigned)(j1  * (WPAD * 4));
                    unsigned int a2  = lbase + (unsigned)(j2  * (WPAD * 4));
                    unsigned int a3  = lbase + (unsigned)(j3  * (WPAD * 4));
                    unsigned int a4  = lbase + (unsigned)(j4  * (WPAD * 4));
                    unsigned int a5  = lbase + (unsigned)(j5  * (WPAD * 4));
                    unsigned int a6  = lbase + (unsigned)(j6  * (WPAD * 4));
                    unsigned int a7  = lbase + (unsigned)(j7  * (WPAD * 4));
                    unsigned int a8  = lbase + (unsigned)(j8  * (WPAD * 4));
                    unsigned int a9  = lbase + (unsigned)(j9  * (WPAD * 4));
                    unsigned int a10 = lbase + (unsigned)(j10 * (WPAD * 4));
                    unsigned int a11 = lbase + (unsigned)(j11 * (WPAD * 4));
                    unsigned int a12 = lbase + (unsigned)(j12 * (WPAD * 4));
                    unsigned int a13 = lbase + (unsigned)(j13 * (WPAD * 4));
                    unsigned int a14 = lbase + (unsigned)(j14 * (WPAD * 4));
                    unsigned int a15 = lbase + (unsigned)(j15 * (WPAD * 4));

                    float x0,x1,x2,x3,x4,x5,x6,x7,x8,x9,x10,x11,x12,x13,x14,x15;
                    float y0,y1,y2,y3,y4,y5,y6,y7,y8,y9,y10,y11,y12,y13,y14,y15;
                    DS_GATHER8(x0,x1,x2,x3,x4,x5,x6,x7, a0,a1,a2,a3,a4,a5,a6,a7);
                    DS_GATHER8_OFF256(y0,y1,y2,y3,y4,y5,y6,y7,
                                      a0,a1,a2,a3,a4,a5,a6,a7);
                    DS_GATHER8(x8,x9,x10,x11,x12,x13,x14,x15,
                               a8,a9,a10,a11,a12,a13,a14,a15);
                    DS_GATHER8_OFF256(y8,y9,y10,y11,y12,y13,y14,y15,
                                      a8,a9,a10,a11,a12,a13,a14,a15);
                    asm volatile("s_waitcnt lgkmcnt(0)" ::: "memory");
                    __builtin_amdgcn_sched_barrier(0);  // rule #18: pin fold after wait

                    rl += x0;  rh += y0;   rl += x1;  rh += y1;
                    rl += x2;  rh += y2;   rl += x3;  rh += y3;
                    rl += x4;  rh += y4;   rl += x5;  rh += y5;
                    rl += x6;  rh += y6;   rl += x7;  rh += y7;
                    rl += x8;  rh += y8;   rl += x9;  rh += y9;
                    rl += x10; rh += y10;  rl += x11; rh += y11;
                    rl += x12; rh += y12;  rl += x13; rh += y13;
                    rl += x14; rh += y14;  rl += x15; rh += y15;
                    n -= 16;
                }
            }

            float hl = ((dense_l + bil) + rl) + bhl;  // reference add order
            float hh = ((dense_h + bih) + rh) + bhh;
            m0 = __ballot(hl >= 1.0f);
            m1 = __ballot(hh >= 1.0f);
            if (ln == 0) {
                ulonglong2 mv; mv.x = m0; mv.y = m1;
                masks[(size_t)s * T_STEPS + (t0 + t)] = mv;
            }
        }
    }
    if (ln == 0) { ulonglong2 st; st.x = m0; st.y = m1; state[s] = st; }
}

// ---------------------------------------------------------------------------
// Parallel A-term precompute: D2[row][o] = s1_row @ Wi2^T (ascending sparse
// fold, bit-exact). High occupancy hides the LDS gather latency across waves.
// ---------------------------------------------------------------------------
extern "C" __global__ void __launch_bounds__(512, 1)
srnn_dense2(const ulonglong2* __restrict__ masks, const float* __restrict__ Wi2,
            float* __restrict__ D2, int t0, int Tc)
{
    extern __shared__ float WT[];              // Wi2^T [129][WPAD]
    const int tid = threadIdx.x, w = tid >> 6, ln = tid & 63;

    stage_wt_s(WT, Wi2, tid, 512);
    __syncthreads();

    const int rows = NS * Tc;
    for (int r = blockIdx.x * 8 + w; r < rows; r += gridDim.x * 8) {
        int s = r / Tc, trel = r - s * Tc;
        ulonglong2 mv = masks[(size_t)s * T_STEPS + t0 + trel];
        unsigned long long m0 = rfl64(mv.x), m1 = rfl64(mv.y);
        float rl = 0.f, rh = 0.f;
        walk8(WT, ln, m0, m1, rl, rh);
        D2[(size_t)r * HID + ln]      = rl;
        D2[(size_t)r * HID + 64 + ln] = rh;
    }
}

// ---------------------------------------------------------------------------
// Parallel output-term precompute: d[row][o] = s2_row @ Wo^T for o < 20
// (ascending sparse fold; trailing zeros bit-exact). High occupancy.
// ---------------------------------------------------------------------------
extern "C" __global__ void __launch_bounds__(512, 1)
srnn_dense3(const ulonglong2* __restrict__ masks, const float* __restrict__ Wo,
            float* __restrict__ d, int t0, int Tc)
{
    __shared__ float WOt[129 * DOUT];          // Wo^T [129][20] (row 128 = 0)
    const int tid = threadIdx.x, w = tid >> 6, ln = tid & 63;

    for (int i = tid; i < DOUT * HID / 4; i += 512) {
        int o = i >> 5, jq = i & 31;
        float4 v = ((const float4*)Wo)[i];
        WOt[(4 * jq + 0) * DOUT + o] = v.x; WOt[(4 * jq + 1) * DOUT + o] = v.y;
        WOt[(4 * jq + 2) * DOUT + o] = v.z; WOt[(4 * jq + 3) * DOUT + o] = v.w;
    }
    for (int i = tid; i < DOUT; i += 512) WOt[128 * DOUT + i] = 0.f;
    __syncthreads();

    const int rows = NS * Tc;
    for (int r = blockIdx.x * 8 + w; r < rows; r += gridDim.x * 8) {
        int s = r / Tc, trel = r - s * Tc;
        ulonglong2 mv = masks[(size_t)s * T_STEPS + t0 + trel];
        unsigned long long lo = rfl64(mv.x), hi = rfl64(mv.y);
        if (ln < DOUT) {
            float dd = 0.f;
            int no = __popcll(lo) + __popcll(hi);
            while (no > 0) {
                int jj[8];
                #pragma unroll
                for (int u = 0; u < 8; ++u) jj[u] = next128z(lo, hi);
                float vv[8];
                #pragma unroll
                for (int u = 0; u < 8; ++u) vv[u] = WOt[jj[u] * DOUT + ln];
                #pragma unroll
                for (int u = 0; u < 8; ++u) dd += vv[u];
                no -= 8;
            }
            d[(size_t)r * DOUT + ln] = dd;
        }
    }
}

// ---------------------------------------------------------------------------
// Serial output accumulation, exact reference order per (s,o):
//   acc = (acc + d_t) + bo, t ascending; 8-deep prefetch (proven idiom).
// ---------------------------------------------------------------------------
extern "C" __global__ void __launch_bounds__(128, 1)
srnn_reduce(const float* __restrict__ d, const float* __restrict__ bo,
            float* __restrict__ accbuf, float* __restrict__ out,
            int Tc, int first, int last)
{
    const int tid = threadIdx.x, w = tid >> 6, ln = tid & 63;
    const int s = 2 * blockIdx.x + w;
    if (ln >= DOUT) return;

    const float bol = bo[ln];
    float acc = first ? 0.f : accbuf[s * DOUT + ln];
    const float* drow = d + (size_t)s * Tc * DOUT + ln;

    float pf[8];
    #pragma unroll
    for (int p = 0; p < 8; ++p) { int ti = p < Tc ? p : Tc - 1; pf[p] = drow[ti * DOUT]; }

    for (int tt = 0; tt < Tc; tt += 8) {
        #pragma unroll
        for (int u = 0; u < 8; ++u) {
            int t = tt + u;
            if (t >= Tc) break;                       // uniform among active lanes
            float dv = pf[u];
            int tp = (t + 8 < Tc) ? t + 8 : Tc - 1;
            pf[u] = drow[tp * DOUT];
            acc += dv;                                // (acc + dot) ...
            acc += bol;                               //  ... + bo
        }
    }
    if (last) out[s * DOUT + ln] = acc / (float)T_STEPS;
    else      accbuf[s * DOUT + ln] = acc;
}

// ---------------------------------------------------------------------------
extern "C" void kernel_launch(void* const* d_in, const int* in_sizes, int n_in,
                              void* d_out, int out_size, void* d_ws, size_t ws_size,
                              hipStream_t stream) {
    const float* x   = (const float*)d_in[0];
    const float* Wi1 = (const float*)d_in[1];
    const float* bi1 = (const float*)d_in[2];
    const float* Wh1 = (const float*)d_in[3];
    const float* bh1 = (const float*)d_in[4];
    const float* Wi2 = (const float*)d_in[5];
    const float* bi2 = (const float*)d_in[6];
    const float* Wh2 = (const float*)d_in[7];
    const float* bh2 = (const float*)d_in[8];
    const float* Wo  = (const float*)d_in[9];
    const float* bo  = (const float*)d_in[10];
    float* out = (float*)d_out;

    // ws layout: [masks 8.192MB][st1 8KB][st2 8KB][acc 40KB][D/d chunk buffer]
    const size_t mask_bytes = (size_t)NS * T_STEPS * sizeof(ulonglong2);
    const size_t st_bytes   = (size_t)NS * sizeof(ulonglong2);
    const size_t acc_bytes  = (size_t)NS * DOUT * sizeof(float);
    ulonglong2* masks  = (ulonglong2*)d_ws;
    ulonglong2* state  = (ulonglong2*)((char*)d_ws + mask_bytes);
    ulonglong2* state2 = (ulonglong2*)((char*)d_ws + mask_bytes + st_bytes);
    float* accbuf = (float*)((char*)d_ws + mask_bytes + 2 * st_bytes);
    float* D = (float*)((char*)d_ws + mask_bytes + 2 * st_bytes + acc_bytes);

    const size_t head = mask_bytes + 2 * st_bytes + acc_bytes;
    size_t avail = ws_size > head ? ws_size - head : 0;
    const size_t bytes_per_t = (size_t)NS * HID * sizeof(float);  // 256 KB
    long tcmax = (long)(avail / bytes_per_t);
    static const int divs[] = {1000, 500, 250, 200, 125, 100, 50, 40, 25, 20, 10, 8, 5, 4, 2, 1};
    int Tc = 1;
    for (int i = 0; i < 16; ++i) if (divs[i] <= tcmax) { Tc = divs[i]; break; }

    const int lds0  = (128 * XPAD + HID * HID) * (int)sizeof(float);
    const int lds1  = (129 * WPAD) * (int)sizeof(float);
    hipFuncSetAttribute((const void*)srnn_dense,
                        hipFuncAttributeMaxDynamicSharedMemorySize, lds0);
    hipFuncSetAttribute((const void*)srnn_layer,
                        hipFuncAttributeMaxDynamicSharedMemorySize, lds1);
    hipFuncSetAttribute((const void*)srnn_dense2,
                        hipFuncAttributeMaxDynamicSharedMemorySize, lds1);

    // Phase 1: dense input-term + layer-1 recurrence (writes s1 masks).
    for (int t0 = 0; t0 < T_STEPS; t0 += Tc) {
        srnn_dense<<<4 * Tc, 512, lds0, stream>>>(x, Wi1, D, t0, Tc);
        srnn_layer<<<NS / 2, 128, lds1, stream>>>(D, Wh1, bi1, bh1, masks, state,
                                                  t0, Tc, t0 == 0 ? 1 : 0);
    }
    // Phase 2: parallel A-term (s1 @ Wi2^T) + layer-2 recurrence.
    // dense2 consumes the chunk's s1 masks BEFORE srnn_layer overwrites the
    // same slots with s2 masks (stream-ordered, in-place safe).
    for (int t0 = 0; t0 < T_STEPS; t0 += Tc) {
        srnn_dense2<<<512, 512, lds1, stream>>>(masks, Wi2, D, t0, Tc);
        srnn_layer<<<NS / 2, 128, lds1, stream>>>(D, Wh2, bi2, bh2, masks, state2,
                                                  t0, Tc, t0 == 0 ? 1 : 0);
    }
    // Phase 3: parallel output-term (s2 @ Wo^T) + exact serial accumulation.
    for (int t0 = 0; t0 < T_STEPS; t0 += Tc) {
        srnn_dense3<<<512, 512, 0, stream>>>(masks, Wo, D, t0, Tc);
        srnn_reduce<<<NS / 2, 128, 0, stream>>>(D, bo, accbuf, out, Tc,
                                                t0 == 0 ? 1 : 0,
                                                t0 + Tc >= T_STEPS ? 1 : 0);
    }
}